// Round 6
// baseline (272.428 us; speedup 1.0000x reference)
//
#include <hip/hip_runtime.h>
#include <hip/hip_fp16.h>
#include <math.h>

// Problem constants (fixed by reference setup_inputs)
#define NN 50000      // nodes
#define NE 800000     // edges
#define D  128        // d_in
#define D3 384        // 3*d_in
#define DO 64         // d_out

typedef _Float16 f16x2 __attribute__((ext_vector_type(2)));

__device__ __forceinline__ float dot2acc(unsigned int h2bits, f16x2 w, float acc) {
#if __has_builtin(__builtin_amdgcn_fdot2)
  return __builtin_amdgcn_fdot2(__builtin_bit_cast(f16x2, h2bits), w, acc, false);
#else
  __half2 h = __builtin_bit_cast(__half2, h2bits);
  float2 hf = __half22float2(h);
  return acc + hf.x * (float)w[0] + hf.y * (float)w[1];
#endif
}

// ---------------- setup: fused GRU (blocks 0..63) + init packed (blocks 64..) ------
__global__ __launch_bounds__(256) void setup_kernel(
    const float* __restrict__ init_w, const float* __restrict__ w_ih,
    const float* __restrict__ w_hh, const float* __restrict__ b_ih,
    const float* __restrict__ b_hh, float* __restrict__ W,
    unsigned long long* __restrict__ packed, int* __restrict__ total) {
  if (blockIdx.x >= 64) {
    int i = (blockIdx.x - 64) * 256 + threadIdx.x;
    if (i < NN) packed[i] = (1ULL << 32);  // deg = 1.0 fixed-point, count = 0
    if (i == 0) *total = 0;
    return;
  }
  int idx = blockIdx.x * 256 + threadIdx.x;  // < 16384
  int b = idx >> 7;
  int j = idx & 127;
  const float* xr = init_w + b * D;
  const float* wr_i = w_ih + j * D;
  const float* wz_i = w_ih + (D + j) * D;
  const float* wn_i = w_ih + (2 * D + j) * D;
  const float* wr_h = w_hh + j * D;
  const float* wz_h = w_hh + (D + j) * D;
  const float* wn_h = w_hh + (2 * D + j) * D;
  float ir = 0.f, iz = 0.f, in_ = 0.f, hr = 0.f, hz = 0.f, hn = 0.f;
#pragma unroll 4
  for (int k = 0; k < D; ++k) {
    float xv = xr[k];
    ir += xv * wr_i[k];
    iz += xv * wz_i[k];
    in_ += xv * wn_i[k];
    hr += xv * wr_h[k];
    hz += xv * wz_h[k];
    hn += xv * wn_h[k];
  }
  ir += b_ih[j];       hr += b_hh[j];
  iz += b_ih[D + j];   hz += b_hh[D + j];
  in_ += b_ih[2 * D + j]; hn += b_hh[2 * D + j];
  float r = 1.f / (1.f + expf(-(ir + hr)));
  float z = 1.f / (1.f + expf(-(iz + hz)));
  float n = tanhf(in_ + r * hn);
  W[idx] = (1.f - z) * n + z * init_w[idx];
}

// ---------------- one packed atomic per edge: count + fixed-point degree; rank -----
__global__ __launch_bounds__(256) void count_deg_kernel(const int* __restrict__ col,
                                                        const float* __restrict__ ew,
                                                        unsigned long long* __restrict__ packed,
                                                        int* __restrict__ rank) {
  int e = blockIdx.x * 256 + threadIdx.x;
  if (e < NE) {
    int c = __builtin_nontemporal_load(&col[e]);
    float w = __builtin_nontemporal_load(&ew[e]);
    unsigned long long add = (1ULL << 40) | (unsigned long long)(w * 4294967296.0f);
    unsigned long long old = atomicAdd(&packed[c], add);
    __builtin_nontemporal_store((int)(old >> 40), &rank[e]);
  }
}

// ---------------- dis = rsqrt(deg); cnt; even-aligned bucket starts ----------------
__global__ __launch_bounds__(256) void dis_scan_kernel(
    const unsigned long long* __restrict__ packed, float* __restrict__ dis,
    int* __restrict__ cnt, int* __restrict__ start, int* __restrict__ total) {
  int i = blockIdx.x * 256 + threadIdx.x;
  int lane = threadIdx.x & 63;
  int c = 0;
  float d = 1.0f;
  if (i < NN) {
    unsigned long long p = packed[i];
    c = (int)(p >> 40);
    d = (float)(p & ((1ULL << 40) - 1)) * 0x1p-32f;
  }
  int cp = (c + 1) & ~1;  // pad each bucket to even size -> 16B-aligned starts
  int pre = cp;
#pragma unroll
  for (int off = 1; off < 64; off <<= 1) {
    int t = __shfl_up(pre, off, 64);
    if (lane >= off) pre += t;
  }
  int excl = pre - cp;
  int wtot = __shfl(pre, 63, 64);
  int base = 0;
  if (lane == 63) base = atomicAdd(total, wtot);
  base = __shfl(base, 63, 64);
  if (i < NN) {
    start[i] = base + excl;
    cnt[i] = c;
    dis[i] = rsqrtf(fmaxf(d, 1e-12f));  // d >= 1.0 always (self-loop)
  }
}

// ---------------- bucket scatter, NO atomics: slot = start[col] + rank -------------
__global__ __launch_bounds__(256) void bucket_kernel(
    const int* __restrict__ row, const int* __restrict__ col,
    const float* __restrict__ ew, const int* __restrict__ rank,
    const float* __restrict__ dis, const int* __restrict__ start,
    int2* __restrict__ elist) {
  int e = blockIdx.x * 256 + threadIdx.x;
  if (e >= NE) return;
  int j = __builtin_nontemporal_load(&row[e]);
  int c = __builtin_nontemporal_load(&col[e]);
  float w = __builtin_nontemporal_load(&ew[e]);
  int rk = __builtin_nontemporal_load(&rank[e]);
  float nrm = dis[j] * w * dis[c];
  int slot = start[c] + rk;
  elist[slot] = make_int2(j, __float_as_int(nrm));
}

// ---------------- xw = x @ W  -> fp16 (W staged in LDS) ----------------------------
struct alignas(16) h2x4 { __half2 a, b, c, d; };

__global__ __launch_bounds__(256) void xw_kernel(const float* __restrict__ x,
                                                 const float* __restrict__ W,
                                                 __half* __restrict__ xwh) {
  __shared__ float Wl[D * D];  // 64 KB
  for (int i = threadIdx.x; i < D * D; i += 256) Wl[i] = W[i];
  __syncthreads();
  const int t = threadIdx.x;
  const int rr = t >> 4;           // 0..15
  const int c0 = (t & 15) * 8;     // 0..120
  const int ROWS_PER_TILE = 64;
  for (int base = blockIdx.x * ROWS_PER_TILE; base < NN; base += gridDim.x * ROWS_PER_TILE) {
    float acc[4][8];
#pragma unroll
    for (int q = 0; q < 4; ++q)
#pragma unroll
      for (int j = 0; j < 8; ++j) acc[q][j] = 0.f;
    int r0 = base + rr;
#pragma unroll 4
    for (int k = 0; k < D; ++k) {
      float xv[4];
#pragma unroll
      for (int q = 0; q < 4; ++q) {
        int r = r0 + q * 16;
        xv[q] = (r < NN) ? x[(long)r * D + k] : 0.f;
      }
#pragma unroll
      for (int j = 0; j < 8; ++j) {
        float wv = Wl[k * D + c0 + j];
#pragma unroll
        for (int q = 0; q < 4; ++q) acc[q][j] += xv[q] * wv;
      }
    }
#pragma unroll
    for (int q = 0; q < 4; ++q) {
      int r = r0 + q * 16;
      if (r < NN) {
        h2x4 pk;
        pk.a = __floats2half2_rn(acc[q][0], acc[q][1]);
        pk.b = __floats2half2_rn(acc[q][2], acc[q][3]);
        pk.c = __floats2half2_rn(acc[q][4], acc[q][5]);
        pk.d = __floats2half2_rn(acc[q][6], acc[q][7]);
        *(h2x4*)(xwh + (long)r * D + c0) = pk;
      }
    }
  }
}

// ---------------- gather: h = relu(selfloop + sum norm*xw[j]) -> fp16, NO LDS ------
// One wave per node. Lane l holds dims (2l, 2l+1).
__global__ __launch_bounds__(256) void gather_h_kernel(
    const int* __restrict__ start, const int* __restrict__ cnt,
    const int2* __restrict__ elist, const float* __restrict__ dis,
    const __half* __restrict__ xwh, __half* __restrict__ hout) {
  const int wv = threadIdx.x >> 6;
  const int lane = threadIdx.x & 63;
  const __half2* __restrict__ xw2 = (const __half2*)xwh;  // row stride 64
  unsigned int* __restrict__ h2u = (unsigned int*)hout;
  int gw = blockIdx.x * 4 + wv;
  int nw = gridDim.x * 4;
  for (int i = gw; i < NN; i += nw) {
    float ds = dis[i];
    float sn = ds * ds;  // self-loop norm
    float2 sv = __half22float2(xw2[(long)i * 64 + lane]);
    float a0 = sn * sv.x;
    float a1 = sn * sv.y;
    int s = start[i];          // even -> elist+s is 16B aligned
    int se = s + cnt[i];
    for (; s + 4 <= se; s += 4) {
      uint4 p0 = *(const uint4*)(elist + s);      // edges s, s+1
      uint4 p1 = *(const uint4*)(elist + s + 2);  // edges s+2, s+3
      __half2 v0 = xw2[(long)(int)p0.x * 64 + lane];
      __half2 v1 = xw2[(long)(int)p0.z * 64 + lane];
      __half2 v2 = xw2[(long)(int)p1.x * 64 + lane];
      __half2 v3 = xw2[(long)(int)p1.z * 64 + lane];
      float n0 = __int_as_float(p0.y), n1 = __int_as_float(p0.w);
      float n2 = __int_as_float(p1.y), n3 = __int_as_float(p1.w);
      float2 f0 = __half22float2(v0), f1 = __half22float2(v1);
      float2 f2 = __half22float2(v2), f3 = __half22float2(v3);
      a0 += n0 * f0.x + n1 * f1.x + n2 * f2.x + n3 * f3.x;
      a1 += n0 * f0.y + n1 * f1.y + n2 * f2.y + n3 * f3.y;
    }
    for (; s < se; ++s) {
      int2 e0 = elist[s];
      float2 f0 = __half22float2(xw2[(long)e0.x * 64 + lane]);
      float n0 = __int_as_float(e0.y);
      a0 += n0 * f0.x;
      a1 += n0 * f0.y;
    }
    __half2 hv = __floats2half2_rn(fmaxf(a0, 0.f), fmaxf(a1, 0.f));
    __builtin_nontemporal_store(__builtin_bit_cast(unsigned int, hv),
                                &h2u[(long)i * 64 + lane]);
  }
}

// ---------------- out = h @ lin_w^T + b; lin_w column in 64 VGPRs (half2) ----------
// One wave per node per iter; lane = output channel o. h row read as broadcast x4.
__global__ __launch_bounds__(256) void out_kernel(
    const __half* __restrict__ hh, const float* __restrict__ lin_w,
    const float* __restrict__ lin_b, float* __restrict__ out) {
  const int wv = threadIdx.x >> 6;
  const int lane = threadIdx.x & 63;
  // lane o caches lin_w row o as 64 half2 registers
  f16x2 lt[64];
  const float* wrow = lin_w + lane * D;
#pragma unroll
  for (int kk = 0; kk < 64; ++kk) {
    float2 wp = *(const float2*)(wrow + 2 * kk);
    f16x2 v;
    v[0] = (_Float16)wp.x;
    v[1] = (_Float16)wp.y;
    lt[kk] = v;
  }
  const float bias = lin_b[lane];
  int gw = blockIdx.x * 4 + wv;
  int nw = gridDim.x * 4;
  for (int i = gw; i < NN; i += nw) {
    const uint4* __restrict__ hrow = (const uint4*)(hh + (long)i * D);  // 16 x 16B
    float acc = bias;
#pragma unroll
    for (int c = 0; c < 16; ++c) {
      uint4 v = hrow[c];  // wave-broadcast load
      acc = dot2acc(v.x, lt[4 * c + 0], acc);
      acc = dot2acc(v.y, lt[4 * c + 1], acc);
      acc = dot2acc(v.z, lt[4 * c + 2], acc);
      acc = dot2acc(v.w, lt[4 * c + 3], acc);
    }
    __builtin_nontemporal_store(acc, &out[(long)i * DO + lane]);
  }
}

extern "C" void kernel_launch(void* const* d_in, const int* in_sizes, int n_in,
                              void* d_out, int out_size, void* d_ws, size_t ws_size,
                              hipStream_t stream) {
  const float* x      = (const float*)d_in[0];
  const int*   eidx   = (const int*)d_in[1];
  const float* ew     = (const float*)d_in[2];
  const float* init_w = (const float*)d_in[3];
  const float* w_ih   = (const float*)d_in[4];
  const float* w_hh   = (const float*)d_in[5];
  const float* b_ih   = (const float*)d_in[6];
  const float* b_hh   = (const float*)d_in[7];
  const float* lin_w  = (const float*)d_in[8];
  const float* lin_b  = (const float*)d_in[9];
  float* out = (float*)d_out;
  const int* row = eidx;       // edge_index[0] = source j
  const int* col = eidx + NE;  // edge_index[1] = target i

  // workspace layout (4-byte units; offsets multiples of 64 -> 256B aligned)
  float* ws    = (float*)d_ws;
  float* W     = ws;                           // 16384
  unsigned long long* packed = (unsigned long long*)(W + 16384);  // 50048 u64
  float* dis   = (float*)(packed + 50048);     // 50048
  int*   cnt   = (int*)(dis + 50048);          // 50048
  int*   strt  = cnt + 50048;                  // 50048
  int*   total = strt + 50048;                 // 64
  int*   rank  = total + 64;                   // 800000
  int2*  elist = (int2*)(rank + NE);           // 850048 int2 (padded buckets)
  __half* xwh  = (__half*)(elist + 850048);    // 6,400,000 half (12.8 MB)
  __half* hh   = xwh + (long)NN * D;           // 6,400,000 half (12.8 MB)

  setup_kernel<<<64 + (NN + 255) / 256, 256, 0, stream>>>(init_w, w_ih, w_hh, b_ih,
                                                          b_hh, W, packed, total);
  count_deg_kernel<<<(NE + 255) / 256, 256, 0, stream>>>(col, ew, packed, rank);
  xw_kernel<<<512, 256, 0, stream>>>(x, W, xwh);
  dis_scan_kernel<<<(NN + 255) / 256, 256, 0, stream>>>(packed, dis, cnt, strt, total);
  bucket_kernel<<<(NE + 255) / 256, 256, 0, stream>>>(row, col, ew, rank, dis, strt,
                                                      elist);
  gather_h_kernel<<<2048, 256, 0, stream>>>(strt, cnt, elist, dis, xwh, hh);
  out_kernel<<<512, 256, 0, stream>>>(hh, lin_w, lin_b, out);
}

// Round 7
// 242.455 us; speedup vs baseline: 1.1236x; 1.1236x over previous
//
#include <hip/hip_runtime.h>
#include <hip/hip_fp16.h>
#include <math.h>

// Problem constants (fixed by reference setup_inputs)
#define NN 50000      // nodes
#define NE 800000     // edges
#define D  128        // d_in
#define D3 384        // 3*d_in
#define DO 64         // d_out

typedef _Float16 f16x2 __attribute__((ext_vector_type(2)));

__device__ __forceinline__ float dot2acc(unsigned int h2bits, f16x2 w, float acc) {
#if __has_builtin(__builtin_amdgcn_fdot2)
  return __builtin_amdgcn_fdot2(__builtin_bit_cast(f16x2, h2bits), w, acc, false);
#else
  __half2 h = __builtin_bit_cast(__half2, h2bits);
  float2 hf = __half22float2(h);
  return acc + hf.x * (float)w[0] + hf.y * (float)w[1];
#endif
}

// ---------------- setup: fused GRU (blocks 0..63) + init packed (blocks 64..) ------
__global__ __launch_bounds__(256) void setup_kernel(
    const float* __restrict__ init_w, const float* __restrict__ w_ih,
    const float* __restrict__ w_hh, const float* __restrict__ b_ih,
    const float* __restrict__ b_hh, float* __restrict__ W,
    unsigned long long* __restrict__ packed, int* __restrict__ total) {
  if (blockIdx.x >= 64) {
    int i = (blockIdx.x - 64) * 256 + threadIdx.x;
    if (i < NN) packed[i] = (1ULL << 32);  // deg = 1.0 fixed-point, count = 0
    if (i == 0) *total = 0;
    return;
  }
  int idx = blockIdx.x * 256 + threadIdx.x;  // < 16384
  int b = idx >> 7;
  int j = idx & 127;
  const float* xr = init_w + b * D;
  const float* wr_i = w_ih + j * D;
  const float* wz_i = w_ih + (D + j) * D;
  const float* wn_i = w_ih + (2 * D + j) * D;
  const float* wr_h = w_hh + j * D;
  const float* wz_h = w_hh + (D + j) * D;
  const float* wn_h = w_hh + (2 * D + j) * D;
  float ir = 0.f, iz = 0.f, in_ = 0.f, hr = 0.f, hz = 0.f, hn = 0.f;
#pragma unroll 4
  for (int k = 0; k < D; ++k) {
    float xv = xr[k];
    ir += xv * wr_i[k];
    iz += xv * wz_i[k];
    in_ += xv * wn_i[k];
    hr += xv * wr_h[k];
    hz += xv * wz_h[k];
    hn += xv * wn_h[k];
  }
  ir += b_ih[j];       hr += b_hh[j];
  iz += b_ih[D + j];   hz += b_hh[D + j];
  in_ += b_ih[2 * D + j]; hn += b_hh[2 * D + j];
  float r = 1.f / (1.f + expf(-(ir + hr)));
  float z = 1.f / (1.f + expf(-(iz + hz)));
  float n = tanhf(in_ + r * hn);
  W[idx] = (1.f - z) * n + z * init_w[idx];
}

// ---------------- one packed atomic per edge: count + fixed-point degree; rank -----
__global__ __launch_bounds__(256) void count_deg_kernel(const int* __restrict__ col,
                                                        const float* __restrict__ ew,
                                                        unsigned long long* __restrict__ packed,
                                                        int* __restrict__ rank) {
  int e = blockIdx.x * 256 + threadIdx.x;
  if (e < NE) {
    int c = __builtin_nontemporal_load(&col[e]);
    float w = __builtin_nontemporal_load(&ew[e]);
    unsigned long long add = (1ULL << 40) | (unsigned long long)(w * 4294967296.0f);
    unsigned long long old = atomicAdd(&packed[c], add);
    __builtin_nontemporal_store((int)(old >> 40), &rank[e]);
  }
}

// ---------------- dis = rsqrt(deg); cnt; even-aligned bucket starts ----------------
__global__ __launch_bounds__(256) void dis_scan_kernel(
    const unsigned long long* __restrict__ packed, float* __restrict__ dis,
    int* __restrict__ cnt, int* __restrict__ start, int* __restrict__ total) {
  int i = blockIdx.x * 256 + threadIdx.x;
  int lane = threadIdx.x & 63;
  int c = 0;
  float d = 1.0f;
  if (i < NN) {
    unsigned long long p = packed[i];
    c = (int)(p >> 40);
    d = (float)(p & ((1ULL << 40) - 1)) * 0x1p-32f;
  }
  int cp = (c + 1) & ~1;  // pad each bucket to even size -> 16B-aligned starts
  int pre = cp;
#pragma unroll
  for (int off = 1; off < 64; off <<= 1) {
    int t = __shfl_up(pre, off, 64);
    if (lane >= off) pre += t;
  }
  int excl = pre - cp;
  int wtot = __shfl(pre, 63, 64);
  int base = 0;
  if (lane == 63) base = atomicAdd(total, wtot);
  base = __shfl(base, 63, 64);
  if (i < NN) {
    start[i] = base + excl;
    cnt[i] = c;
    dis[i] = rsqrtf(fmaxf(d, 1e-12f));  // d >= 1.0 always (self-loop)
  }
}

// ---------------- bucket scatter, NO atomics: slot = start[col] + rank -------------
__global__ __launch_bounds__(256) void bucket_kernel(
    const int* __restrict__ row, const int* __restrict__ col,
    const float* __restrict__ ew, const int* __restrict__ rank,
    const float* __restrict__ dis, const int* __restrict__ start,
    int2* __restrict__ elist) {
  int e = blockIdx.x * 256 + threadIdx.x;
  if (e >= NE) return;
  int j = __builtin_nontemporal_load(&row[e]);
  int c = __builtin_nontemporal_load(&col[e]);
  float w = __builtin_nontemporal_load(&ew[e]);
  int rk = __builtin_nontemporal_load(&rank[e]);
  float nrm = dis[j] * w * dis[c];
  int slot = start[c] + rk;
  elist[slot] = make_int2(j, __float_as_int(nrm));
}

// ---------------- xw = x @ W  -> fp16 (W staged in LDS) ----------------------------
struct alignas(16) h2x4 { __half2 a, b, c, d; };

__global__ __launch_bounds__(256) void xw_kernel(const float* __restrict__ x,
                                                 const float* __restrict__ W,
                                                 __half* __restrict__ xwh) {
  __shared__ float Wl[D * D];  // 64 KB
  for (int i = threadIdx.x; i < D * D; i += 256) Wl[i] = W[i];
  __syncthreads();
  const int t = threadIdx.x;
  const int rr = t >> 4;           // 0..15
  const int c0 = (t & 15) * 8;     // 0..120
  const int ROWS_PER_TILE = 64;
  for (int base = blockIdx.x * ROWS_PER_TILE; base < NN; base += gridDim.x * ROWS_PER_TILE) {
    float acc[4][8];
#pragma unroll
    for (int q = 0; q < 4; ++q)
#pragma unroll
      for (int j = 0; j < 8; ++j) acc[q][j] = 0.f;
    int r0 = base + rr;
#pragma unroll 4
    for (int k = 0; k < D; ++k) {
      float xv[4];
#pragma unroll
      for (int q = 0; q < 4; ++q) {
        int r = r0 + q * 16;
        xv[q] = (r < NN) ? x[(long)r * D + k] : 0.f;
      }
#pragma unroll
      for (int j = 0; j < 8; ++j) {
        float wv = Wl[k * D + c0 + j];
#pragma unroll
        for (int q = 0; q < 4; ++q) acc[q][j] += xv[q] * wv;
      }
    }
#pragma unroll
    for (int q = 0; q < 4; ++q) {
      int r = r0 + q * 16;
      if (r < NN) {
        h2x4 pk;
        pk.a = __floats2half2_rn(acc[q][0], acc[q][1]);
        pk.b = __floats2half2_rn(acc[q][2], acc[q][3]);
        pk.c = __floats2half2_rn(acc[q][4], acc[q][5]);
        pk.d = __floats2half2_rn(acc[q][6], acc[q][7]);
        *(h2x4*)(xwh + (long)r * D + c0) = pk;
      }
    }
  }
}

// ---------------- fused: gather h (regs) -> relu -> 1KB LDS -> @ lin_w^T + b -------
// One wave per node. Lane l holds dims (2l, 2l+1) during gather; lane o = output
// channel during projection. lin_w row o lives in 64 VGPRs (half2) per lane.
__global__ __launch_bounds__(256) void gather_out_kernel(
    const int* __restrict__ start, const int* __restrict__ cnt,
    const int2* __restrict__ elist, const float* __restrict__ dis,
    const __half* __restrict__ xwh, const float* __restrict__ lin_w,
    const float* __restrict__ lin_b, float* __restrict__ out) {
  __shared__ unsigned int hb[4][64];  // per-wave packed-half2 h row, 1 KB
  const int wv = threadIdx.x >> 6;
  const int lane = threadIdx.x & 63;
  // lane o caches lin_w row o as 64 half2 registers
  f16x2 lt[64];
  {
    const float* wrow = lin_w + lane * D;
#pragma unroll
    for (int kk = 0; kk < 64; ++kk) {
      float2 wp = *(const float2*)(wrow + 2 * kk);
      f16x2 v;
      v[0] = (_Float16)wp.x;
      v[1] = (_Float16)wp.y;
      lt[kk] = v;
    }
  }
  const float bias = lin_b[lane];
  const __half2* __restrict__ xw2 = (const __half2*)xwh;  // row stride 64
  int gw = blockIdx.x * 4 + wv;
  int nw = gridDim.x * 4;
  for (int i = gw; i < NN; i += nw) {
    float ds = dis[i];
    float sn = ds * ds;  // self-loop norm
    float2 sv = __half22float2(xw2[(long)i * 64 + lane]);
    float a0 = sn * sv.x;
    float a1 = sn * sv.y;
    int s = start[i];          // even -> elist+s is 16B aligned
    int se = s + cnt[i];
    for (; s + 4 <= se; s += 4) {
      uint4 p0 = *(const uint4*)(elist + s);      // edges s, s+1
      uint4 p1 = *(const uint4*)(elist + s + 2);  // edges s+2, s+3
      __half2 v0 = xw2[(long)(int)p0.x * 64 + lane];
      __half2 v1 = xw2[(long)(int)p0.z * 64 + lane];
      __half2 v2 = xw2[(long)(int)p1.x * 64 + lane];
      __half2 v3 = xw2[(long)(int)p1.z * 64 + lane];
      float n0 = __int_as_float(p0.y), n1 = __int_as_float(p0.w);
      float n2 = __int_as_float(p1.y), n3 = __int_as_float(p1.w);
      float2 f0 = __half22float2(v0), f1 = __half22float2(v1);
      float2 f2 = __half22float2(v2), f3 = __half22float2(v3);
      a0 += n0 * f0.x + n1 * f1.x + n2 * f2.x + n3 * f3.x;
      a1 += n0 * f0.y + n1 * f1.y + n2 * f2.y + n3 * f3.y;
    }
    for (; s < se; ++s) {
      int2 e0 = elist[s];
      float2 f0 = __half22float2(xw2[(long)e0.x * 64 + lane]);
      float n0 = __int_as_float(e0.y);
      a0 += n0 * f0.x;
      a1 += n0 * f0.y;
    }
    // relu + pack to half2, exchange through LDS (1 write + 16 b128 reads per node)
    __half2 hv = __floats2half2_rn(fmaxf(a0, 0.f), fmaxf(a1, 0.f));
    hb[wv][lane] = __builtin_bit_cast(unsigned int, hv);
    // same-wave LDS RAW: drain ds_write before reads (no cross-wave sharing)
    asm volatile("s_waitcnt lgkmcnt(0)" ::: "memory");
    float ac0 = bias, ac1 = 0.f, ac2 = 0.f, ac3 = 0.f;
    const uint4* hrow = (const uint4*)&hb[wv][0];
#pragma unroll
    for (int c = 0; c < 16; ++c) {
      uint4 v = hrow[c];  // broadcast read, conflict-free
      ac0 = dot2acc(v.x, lt[4 * c + 0], ac0);
      ac1 = dot2acc(v.y, lt[4 * c + 1], ac1);
      ac2 = dot2acc(v.z, lt[4 * c + 2], ac2);
      ac3 = dot2acc(v.w, lt[4 * c + 3], ac3);
    }
    // drain reads before next iteration's ds_write reuses the buffer
    asm volatile("s_waitcnt lgkmcnt(0)" ::: "memory");
    __builtin_nontemporal_store((ac0 + ac1) + (ac2 + ac3),
                                &out[(long)i * DO + lane]);
  }
}

extern "C" void kernel_launch(void* const* d_in, const int* in_sizes, int n_in,
                              void* d_out, int out_size, void* d_ws, size_t ws_size,
                              hipStream_t stream) {
  const float* x      = (const float*)d_in[0];
  const int*   eidx   = (const int*)d_in[1];
  const float* ew     = (const float*)d_in[2];
  const float* init_w = (const float*)d_in[3];
  const float* w_ih   = (const float*)d_in[4];
  const float* w_hh   = (const float*)d_in[5];
  const float* b_ih   = (const float*)d_in[6];
  const float* b_hh   = (const float*)d_in[7];
  const float* lin_w  = (const float*)d_in[8];
  const float* lin_b  = (const float*)d_in[9];
  float* out = (float*)d_out;
  const int* row = eidx;       // edge_index[0] = source j
  const int* col = eidx + NE;  // edge_index[1] = target i

  // workspace layout (4-byte units; offsets multiples of 64 -> 256B aligned)
  float* ws    = (float*)d_ws;
  float* W     = ws;                           // 16384
  unsigned long long* packed = (unsigned long long*)(W + 16384);  // 50048 u64
  float* dis   = (float*)(packed + 50048);     // 50048
  int*   cnt   = (int*)(dis + 50048);          // 50048
  int*   strt  = cnt + 50048;                  // 50048
  int*   total = strt + 50048;                 // 64
  int*   rank  = total + 64;                   // 800000
  int2*  elist = (int2*)(rank + NE);           // 850048 int2 (padded buckets)
  __half* xwh  = (__half*)(elist + 850048);    // 6,400,000 half (12.8 MB)

  setup_kernel<<<64 + (NN + 255) / 256, 256, 0, stream>>>(init_w, w_ih, w_hh, b_ih,
                                                          b_hh, W, packed, total);
  count_deg_kernel<<<(NE + 255) / 256, 256, 0, stream>>>(col, ew, packed, rank);
  xw_kernel<<<512, 256, 0, stream>>>(x, W, xwh);
  dis_scan_kernel<<<(NN + 255) / 256, 256, 0, stream>>>(packed, dis, cnt, strt, total);
  bucket_kernel<<<(NE + 255) / 256, 256, 0, stream>>>(row, col, ew, rank, dis, strt,
                                                      elist);
  gather_out_kernel<<<2048, 256, 0, stream>>>(strt, cnt, elist, dis, xwh,
                                              lin_w, lin_b, out);
}